// Round 7
// baseline (260.268 us; speedup 1.0000x reference)
//
#include <hip/hip_runtime.h>
#include <hip/hip_bf16.h>
#include <hip/hip_cooperative_groups.h>

namespace cg = cooperative_groups;

// Problem constants
constexpr int   D      = 512;
constexpr int   NP     = 128;
constexpr float ALPHA  = 1.0f;
constexpr float EPS    = 1e-9f;
constexpr float INV_CNT = 1.0f / (32.0f * 128.0f * 128.0f);  // 1/524288

// ws layout (bytes)
constexpr size_t NORM_OFF = 0;           // 8192*512*2 = 8388608 (bf16)
constexpr size_t PART_OFF = 8388608;     // 256*4

typedef short bf16x8 __attribute__((ext_vector_type(8)));
typedef float f32x4  __attribute__((ext_vector_type(4)));

// round-to-nearest-even f32 -> bf16 bits
__device__ __forceinline__ short f2bf(float f) {
    unsigned u = __builtin_bit_cast(unsigned, f);
    unsigned r = (u + 0x7FFFu + ((u >> 16) & 1u)) >> 16;
    return (short)r;
}

// async global->LDS, 16B per lane; dest = uniform base + lane*16 (HW rule)
typedef __attribute__((address_space(3))) char lds_char;
typedef const __attribute__((address_space(1))) char g_char;
__device__ __forceinline__ void glds16(const void* g, void* l) {
    __builtin_amdgcn_global_load_lds((g_char*)g, (lds_char*)l, 16, 0, 0);
}

// ---------------------------------------------------------------------------
// Single cooperative kernel. grid = 256 blocks x 512 threads, 1 block/CU.
// Phase 1: normalize 32 rows/block (fp32 -> bf16), grid sync.
// Phase 2: fused gram+loss (verified R6 structure):
//   XCD-bijective block->batch/chunk swizzle; A panel (32 rows) in VGPRs;
//   B wave-private glds triple-buffer (BK=32), distance-2 prefetch with
//   hand-counted vmcnt; chunk-XOR swizzle on global SOURCE + ds_read pos.
//   P(32x256) -> LDS overlay; per-row bitonic sort + prefix + binsearch.
// Phase 3: block 0 reduces 256 partials -> out[0].
constexpr int PSTR = 260;                 // padded f32 row stride for P
constexpr int BBUF = 16384;               // one B slice buffer (256 rows x 64B)

__global__ __launch_bounds__(512, 2) void k_all(const float* __restrict__ latent,
                                                short* __restrict__ nrm,
                                                float* __restrict__ part,
                                                float* __restrict__ out) {
    __shared__ __align__(16) char smem[49184];   // B 3x16K; P overlays; red @49152

    const int p    = blockIdx.x;
    const int w    = threadIdx.x >> 6;
    const int lane = threadIdx.x & 63;
    const int fr   = lane & 15;
    const int kg   = lane >> 4;

    // ---------------- Phase 1: normalize rows [p*32, p*32+32) ----------------
    #pragma unroll
    for (int rr = 0; rr < 4; rr++) {
        const int r = p * 32 + w * 4 + rr;
        const float4* src = (const float4*)(latent + (size_t)r * D);
        float4 x0 = src[2 * lane];
        float4 x1 = src[2 * lane + 1];
        float ss = x0.x*x0.x + x0.y*x0.y + x0.z*x0.z + x0.w*x0.w
                 + x1.x*x1.x + x1.y*x1.y + x1.z*x1.z + x1.w*x1.w;
        #pragma unroll
        for (int o = 32; o > 0; o >>= 1) ss += __shfl_xor(ss, o, 64);
        const float inv = rsqrtf(ss);
        bf16x8 v;
        v[0] = f2bf(x0.x * inv); v[1] = f2bf(x0.y * inv);
        v[2] = f2bf(x0.z * inv); v[3] = f2bf(x0.w * inv);
        v[4] = f2bf(x1.x * inv); v[5] = f2bf(x1.y * inv);
        v[6] = f2bf(x1.z * inv); v[7] = f2bf(x1.w * inv);
        ((bf16x8*)(nrm + (size_t)r * D))[lane] = v;
    }

    __threadfence();                 // release: push nrm writes to device scope
    cg::this_grid().sync();
    __threadfence();                 // acquire: invalidate stale lines

    // ---------------- Phase 2: fused gram+loss ----------------
    const int slot  = p >> 3;
    const int b     = (p & 7) * 4 + (slot & 3);   // XCD-bijective: 4 batches/XCD
    const int chunk = slot >> 2;

    const short* base = nrm + (size_t)b * 256 * D;
    const int cg_ = w * 32;                       // this wave's 32 B-rows

    // A panel to registers (rows chunk*16+fr and 128+chunk*16+fr)
    const short* gA0 = base + (size_t)(chunk * 16 + fr) * D + 8 * kg;
    const short* gA1 = gA0 + (size_t)128 * D;
    bf16x8 a0r[16], a1r[16];
    #pragma unroll
    for (int s = 0; s < 16; s++) {
        a0r[s] = *(const bf16x8*)(gA0 + s * 32);
        a1r[s] = *(const bf16x8*)(gA1 + s * 32);
    }

    // B staging: slice ks -> buffer bi (wave-private region)
    auto stageB = [&](int ks, int bi) {
        #pragma unroll
        for (int t = 0; t < 2; t++) {
            const int sl  = t * 64 + lane;        // 16B chunk slot in wave region
            const int row = sl >> 2;              // 0..31
            const int pp  = sl & 3;               // stored position
            const int gch = pp ^ (row & 3);       // pre-swizzled source chunk
            const short* src = base + (size_t)(cg_ + row) * D + ks * 32 + gch * 8;
            glds16(src, &smem[bi * BBUF + w * 2048 + t * 1024]);  // +lane*16 implicit
        }
    };

    f32x4 acc00 = {0.f,0.f,0.f,0.f}, acc01 = {0.f,0.f,0.f,0.f};
    f32x4 acc10 = {0.f,0.f,0.f,0.f}, acc11 = {0.f,0.f,0.f,0.f};

    stageB(0, 0);
    stageB(1, 1);
    asm volatile("s_waitcnt vmcnt(2)" ::: "memory");
    __builtin_amdgcn_sched_barrier(0);

    const int pb = (kg ^ (fr & 3)) * 16;          // swizzled read position (bytes)
    #pragma unroll
    for (int s = 0; s < 16; s++) {
        if (s < 14) stageB(s + 2, (s + 2) % 3);
        const int bo = (s % 3) * BBUF + w * 2048;
        bf16x8 b0 = *(const bf16x8*)&smem[bo + fr * 64 + pb];
        bf16x8 b1 = *(const bf16x8*)&smem[bo + (16 + fr) * 64 + pb];
        acc00 = __builtin_amdgcn_mfma_f32_16x16x32_bf16(a0r[s], b0, acc00, 0, 0, 0);
        acc01 = __builtin_amdgcn_mfma_f32_16x16x32_bf16(a0r[s], b1, acc01, 0, 0, 0);
        acc10 = __builtin_amdgcn_mfma_f32_16x16x32_bf16(a1r[s], b0, acc10, 0, 0, 0);
        acc11 = __builtin_amdgcn_mfma_f32_16x16x32_bf16(a1r[s], b1, acc11, 0, 0, 0);
        if (s < 14)      { asm volatile("s_waitcnt vmcnt(2)" ::: "memory"); }
        else if (s == 14){ asm volatile("s_waitcnt vmcnt(0)" ::: "memory"); }
        __builtin_amdgcn_sched_barrier(0);
    }

    __syncthreads();   // B arena dead; P overlays it

    float* P   = (float*)smem;                    // 32 x PSTR f32 = 33280 B
    float* red = (float*)&smem[49152];

    // C/D layout (m89-verified): lane l, reg q -> row (l>>4)*4+q, col l&15
    {
        const int rw = kg * 4;
        const int cw = cg_ + fr;
        #pragma unroll
        for (int q = 0; q < 4; q++) P[(rw + q) * PSTR + cw]            = acc00[q];
        #pragma unroll
        for (int q = 0; q < 4; q++) P[(rw + q) * PSTR + cw + 16]      = acc01[q];
        #pragma unroll
        for (int q = 0; q < 4; q++) P[(16 + rw + q) * PSTR + cw]      = acc10[q];
        #pragma unroll
        for (int q = 0; q < 4; q++) P[(16 + rw + q) * PSTR + cw + 16] = acc11[q];
    }
    __syncthreads();

    // Loss: 4 rows per wave, wave-private (verified rounds 3-6)
    float wacc = 0.f;
    #pragma unroll
    for (int rr = 0; rr < 4; rr++) {
        const int r      = w * 4 + rr;
        const int pd_off = (r < 16) ? 0 : 128;
        const int pn_off = 128 - pd_off;
        float* prow = &P[r * PSTR];

        const float g0 = prow[pd_off + lane];
        const float g1 = prow[pd_off + lane + 64];
        float v0 = prow[pn_off + lane];
        float v1 = prow[pn_off + lane + 64];

        // bitonic sort ascending (2 elems/lane)
        #pragma unroll
        for (int kk = 2; kk <= 128; kk <<= 1) {
            if (kk == 128) {
                const float lo = fminf(v0, v1);
                const float hi = fmaxf(v0, v1);
                v0 = lo; v1 = hi;
            }
            #pragma unroll
            for (int j = (kk == 128 ? 32 : (kk >> 1)); j >= 1; j >>= 1) {
                const float p0 = __shfl_xor(v0, j, 64);
                const float p1 = __shfl_xor(v1, j, 64);
                const bool up0 = (lane & kk) == 0;
                const bool up1 = ((lane + 64) & kk) == 0;
                const bool lower = (lane & j) == 0;
                v0 = (up0 == lower) ? fminf(v0, p0) : fmaxf(v0, p0);
                v1 = (up1 == lower) ? fminf(v1, p1) : fmaxf(v1, p1);
            }
        }

        // inclusive prefix scans of the two halves
        float inc0 = v0, inc1 = v1;
        #pragma unroll
        for (int o = 1; o < 64; o <<= 1) {
            const float t0 = __shfl_up(inc0, o, 64);
            const float t1 = __shfl_up(inc1, o, 64);
            if (lane >= o) { inc0 += t0; inc1 += t1; }
        }
        const float tot0  = __shfl(inc0, 63, 64);
        const float total = tot0 + __shfl(inc1, 63, 64);

        // write sorted s[0:128] and exclusive prefix pre[0:129]
        prow[lane]            = v0;
        prow[64 + lane]       = v1;
        prow[130 + 1 + lane]  = inc0;
        prow[130 + 65 + lane] = tot0 + inc1;
        if (lane == 0) prow[130] = 0.f;

        // per-j: rank via guarded binary search, closed-form num/den
        #pragma unroll
        for (int h = 0; h < 2; h++) {
            const float g   = h ? g1 : g0;
            const float tau = g - 0.5f * ALPHA;
            const float a   = ALPHA - 2.f * g;
            int pos = 0;
            #pragma unroll
            for (int st = 128; st > 0; st >>= 1) {
                const int nidx = pos + st;
                const float sv = prow[nidx - 1];
                pos = ((nidx <= 128) && (sv <= tau)) ? nidx : pos;
            }
            const float cnt = (float)(128 - pos);
            const float pre = prow[130 + pos];
            const float num = cnt * a + 2.f * (total - pre);
            wacc += num / (cnt + EPS);
        }
    }

    #pragma unroll
    for (int o = 32; o > 0; o >>= 1) wacc += __shfl_xor(wacc, o, 64);
    if (lane == 0) red[w] = wacc;
    __syncthreads();
    if (threadIdx.x == 0) {
        float s = 0.f;
        #pragma unroll
        for (int i = 0; i < 8; i++) s += red[i];
        part[p] = s;
    }

    __threadfence();
    cg::this_grid().sync();
    __threadfence();

    // ---------------- Phase 3: block 0 reduces 256 partials ----------------
    if (p == 0) {
        float s = (threadIdx.x < 256) ? part[threadIdx.x] : 0.f;
        #pragma unroll
        for (int o = 32; o > 0; o >>= 1) s += __shfl_xor(s, o, 64);
        if (lane == 0) red[w] = s;
        __syncthreads();
        if (threadIdx.x == 0) {
            float t = 0.f;
            #pragma unroll
            for (int i = 0; i < 8; i++) t += red[i];
            out[0] = t * INV_CNT;
        }
    }
}

// ---------------------------------------------------------------------------
extern "C" void kernel_launch(void* const* d_in, const int* in_sizes, int n_in,
                              void* d_out, int out_size, void* d_ws, size_t ws_size,
                              hipStream_t stream) {
    const float* latent = (const float*)d_in[0];
    float* out = (float*)d_out;
    char* wsb = (char*)d_ws;
    short* nrm  = (short*)(wsb + NORM_OFF);
    float* part = (float*)(wsb + PART_OFF);

    void* args[] = { (void*)&latent, (void*)&nrm, (void*)&part, (void*)&out };
    hipLaunchCooperativeKernel((const void*)k_all, dim3(256), dim3(512),
                               args, 0, stream);
}

// Round 8
// 36.691 us; speedup vs baseline: 7.0935x; 7.0935x over previous
//
#include <hip/hip_runtime.h>
#include <hip/hip_bf16.h>

// Problem constants
constexpr int   D      = 512;
constexpr int   NP     = 128;
constexpr float ALPHA  = 1.0f;
constexpr float EPS    = 1e-9f;
constexpr float INV_CNT = 1.0f / (32.0f * 128.0f * 128.0f);  // 1/524288

// ws layout (bytes)
constexpr size_t NORM_OFF = 0;           // 8192*512*2 = 8388608 (bf16)
constexpr size_t PART_OFF = 8388608;     // 256*4

typedef short bf16x8 __attribute__((ext_vector_type(8)));
typedef float f32x4  __attribute__((ext_vector_type(4)));

// round-to-nearest-even f32 -> bf16 bits
__device__ __forceinline__ short f2bf(float f) {
    unsigned u = __builtin_bit_cast(unsigned, f);
    unsigned r = (u + 0x7FFFu + ((u >> 16) & 1u)) >> 16;
    return (short)r;
}

// async global->LDS, 16B per lane; dest = uniform base + lane*16 (HW rule)
typedef __attribute__((address_space(3))) char lds_char;
typedef const __attribute__((address_space(1))) char g_char;
__device__ __forceinline__ void glds16(const void* g, void* l) {
    __builtin_amdgcn_global_load_lds((g_char*)g, (lds_char*)l, 16, 0, 0);
}

// ---------------------------------------------------------------------------
// K1: row-normalize fp32 -> bf16. One wave per row. 2048 blocks x 256.
__global__ __launch_bounds__(256) void k_normalize(const float* __restrict__ in,
                                                   short* __restrict__ out) {
    const int wid  = threadIdx.x >> 6;
    const int lane = threadIdx.x & 63;
    const int r    = blockIdx.x * 4 + wid;
    const float4* src = (const float4*)(in + (size_t)r * D);
    float4 x0 = src[2 * lane];
    float4 x1 = src[2 * lane + 1];
    float ss = x0.x*x0.x + x0.y*x0.y + x0.z*x0.z + x0.w*x0.w
             + x1.x*x1.x + x1.y*x1.y + x1.z*x1.z + x1.w*x1.w;
    #pragma unroll
    for (int o = 32; o > 0; o >>= 1) ss += __shfl_xor(ss, o, 64);
    const float inv = rsqrtf(ss);
    bf16x8 v;
    v[0] = f2bf(x0.x * inv); v[1] = f2bf(x0.y * inv);
    v[2] = f2bf(x0.z * inv); v[3] = f2bf(x0.w * inv);
    v[4] = f2bf(x1.x * inv); v[5] = f2bf(x1.y * inv);
    v[6] = f2bf(x1.z * inv); v[7] = f2bf(x1.w * inv);
    ((bf16x8*)(out + (size_t)r * D))[lane] = v;
}

// ---------------------------------------------------------------------------
// K2: fused gram+loss. grid = 256 blocks x 512 threads (XCD-swizzled).
// MFMA phase: A fragments now PIPELINED (3 rotating buffers, 24 VGPRs) instead
// of a 128-VGPR resident panel (R7 counters proved that panel spilled: VGPR=84).
// Per step: 2 A global-loads + 2 B glds share the vmcnt queue (4 ops/step,
// in-order decrement) -> steady-state s_waitcnt vmcnt(4).
// B: wave-private glds triple-buffer, chunk-XOR swizzle on SOURCE + read pos.
// Then P(32x256) -> LDS overlay; loss via sort+prefix+binsearch (verified).
constexpr int PSTR = 260;                 // padded f32 row stride for P
constexpr int BBUF = 16384;               // one B slice buffer (256 rows x 64B)

__global__ __launch_bounds__(512, 2) void k_fused(const short* __restrict__ nrm,
                                                  float* __restrict__ part) {
    __shared__ __align__(16) char smem[49184];   // B 3x16K; P overlays; red @49152

    const int p     = blockIdx.x;
    const int slot  = p >> 3;
    const int b     = (p & 7) * 4 + (slot & 3);   // XCD-bijective: 4 batches/XCD
    const int chunk = slot >> 2;
    const int w     = threadIdx.x >> 6;
    const int lane  = threadIdx.x & 63;
    const int fr    = lane & 15;
    const int kg    = lane >> 4;

    const short* base = nrm + (size_t)b * 256 * D;
    const int cg = w * 32;                        // this wave's 32 B-rows

    // A fragment source (rows chunk*16+fr and 128+chunk*16+fr)
    const short* gA0 = base + (size_t)(chunk * 16 + fr) * D + 8 * kg;
    const short* gA1 = gA0 + (size_t)128 * D;

    // B staging: slice ks -> buffer bi (wave-private region)
    auto stageB = [&](int ks, int bi) {
        #pragma unroll
        for (int t = 0; t < 2; t++) {
            const int sl  = t * 64 + lane;        // 16B chunk slot in wave region
            const int row = sl >> 2;              // 0..31
            const int pp  = sl & 3;               // stored position
            const int gch = pp ^ (row & 3);       // pre-swizzled source chunk
            const short* src = base + (size_t)(cg + row) * D + ks * 32 + gch * 8;
            glds16(src, &smem[bi * BBUF + w * 2048 + t * 1024]);  // +lane*16 implicit
        }
    };

    f32x4 acc00 = {0.f,0.f,0.f,0.f}, acc01 = {0.f,0.f,0.f,0.f};
    f32x4 acc10 = {0.f,0.f,0.f,0.f}, acc11 = {0.f,0.f,0.f,0.f};

    // rotating A buffers (static indices via full unroll)
    bf16x8 aA0[3], aA1[3];

    // prologue: A0,B0,A1,B1 (8 ops); wait until A0+B0 done (4 outstanding)
    aA0[0] = *(const bf16x8*)(gA0 + 0);
    aA1[0] = *(const bf16x8*)(gA1 + 0);
    stageB(0, 0);
    aA0[1] = *(const bf16x8*)(gA0 + 32);
    aA1[1] = *(const bf16x8*)(gA1 + 32);
    stageB(1, 1);
    asm volatile("s_waitcnt vmcnt(4)" ::: "memory");
    __builtin_amdgcn_sched_barrier(0);

    const int pb = (kg ^ (fr & 3)) * 16;          // swizzled read position (bytes)
    #pragma unroll
    for (int s = 0; s < 16; s++) {
        if (s < 14) {
            const int pf = (s + 2) % 3;
            aA0[pf] = *(const bf16x8*)(gA0 + (s + 2) * 32);
            aA1[pf] = *(const bf16x8*)(gA1 + (s + 2) * 32);
            stageB(s + 2, pf);
        }
        const int cur = s % 3;
        const int bo  = cur * BBUF + w * 2048;
        bf16x8 b0 = *(const bf16x8*)&smem[bo + fr * 64 + pb];
        bf16x8 b1 = *(const bf16x8*)&smem[bo + (16 + fr) * 64 + pb];
        acc00 = __builtin_amdgcn_mfma_f32_16x16x32_bf16(aA0[cur], b0, acc00, 0, 0, 0);
        acc01 = __builtin_amdgcn_mfma_f32_16x16x32_bf16(aA0[cur], b1, acc01, 0, 0, 0);
        acc10 = __builtin_amdgcn_mfma_f32_16x16x32_bf16(aA1[cur], b0, acc10, 0, 0, 0);
        acc11 = __builtin_amdgcn_mfma_f32_16x16x32_bf16(aA1[cur], b1, acc11, 0, 0, 0);
        if (s < 14)      { asm volatile("s_waitcnt vmcnt(4)" ::: "memory"); }
        else if (s == 14){ asm volatile("s_waitcnt vmcnt(0)" ::: "memory"); }
        __builtin_amdgcn_sched_barrier(0);
    }

    __syncthreads();   // B arena dead; P overlays it

    float* P   = (float*)smem;                    // 32 x PSTR f32 = 33280 B
    float* red = (float*)&smem[49152];

    // C/D layout (m89-verified): lane l, reg q -> row (l>>4)*4+q, col l&15
    {
        const int rw = kg * 4;
        const int cw = cg + fr;
        #pragma unroll
        for (int q = 0; q < 4; q++) P[(rw + q) * PSTR + cw]            = acc00[q];
        #pragma unroll
        for (int q = 0; q < 4; q++) P[(rw + q) * PSTR + cw + 16]      = acc01[q];
        #pragma unroll
        for (int q = 0; q < 4; q++) P[(16 + rw + q) * PSTR + cw]      = acc10[q];
        #pragma unroll
        for (int q = 0; q < 4; q++) P[(16 + rw + q) * PSTR + cw + 16] = acc11[q];
    }
    __syncthreads();

    // ---- Loss phase: 4 rows per wave, wave-private (verified rounds 3-6) ----
    float wacc = 0.f;
    #pragma unroll
    for (int rr = 0; rr < 4; rr++) {
        const int r      = w * 4 + rr;
        const int pd_off = (r < 16) ? 0 : 128;
        const int pn_off = 128 - pd_off;
        float* prow = &P[r * PSTR];

        const float g0 = prow[pd_off + lane];
        const float g1 = prow[pd_off + lane + 64];
        float v0 = prow[pn_off + lane];
        float v1 = prow[pn_off + lane + 64];

        // bitonic sort ascending (2 elems/lane)
        #pragma unroll
        for (int kk = 2; kk <= 128; kk <<= 1) {
            if (kk == 128) {
                const float lo = fminf(v0, v1);
                const float hi = fmaxf(v0, v1);
                v0 = lo; v1 = hi;
            }
            #pragma unroll
            for (int j = (kk == 128 ? 32 : (kk >> 1)); j >= 1; j >>= 1) {
                const float p0 = __shfl_xor(v0, j, 64);
                const float p1 = __shfl_xor(v1, j, 64);
                const bool up0 = (lane & kk) == 0;
                const bool up1 = ((lane + 64) & kk) == 0;
                const bool lower = (lane & j) == 0;
                v0 = (up0 == lower) ? fminf(v0, p0) : fmaxf(v0, p0);
                v1 = (up1 == lower) ? fminf(v1, p1) : fmaxf(v1, p1);
            }
        }

        // inclusive prefix scans of the two halves
        float inc0 = v0, inc1 = v1;
        #pragma unroll
        for (int o = 1; o < 64; o <<= 1) {
            const float t0 = __shfl_up(inc0, o, 64);
            const float t1 = __shfl_up(inc1, o, 64);
            if (lane >= o) { inc0 += t0; inc1 += t1; }
        }
        const float tot0  = __shfl(inc0, 63, 64);
        const float total = tot0 + __shfl(inc1, 63, 64);

        // write sorted s[0:128] and exclusive prefix pre[0:129]
        prow[lane]            = v0;
        prow[64 + lane]       = v1;
        prow[130 + 1 + lane]  = inc0;
        prow[130 + 65 + lane] = tot0 + inc1;
        if (lane == 0) prow[130] = 0.f;

        // per-j: rank via guarded binary search, closed-form num/den
        #pragma unroll
        for (int h = 0; h < 2; h++) {
            const float g   = h ? g1 : g0;
            const float tau = g - 0.5f * ALPHA;
            const float a   = ALPHA - 2.f * g;
            int pos = 0;
            #pragma unroll
            for (int st = 128; st > 0; st >>= 1) {
                const int nidx = pos + st;
                const float sv = prow[nidx - 1];
                pos = ((nidx <= 128) && (sv <= tau)) ? nidx : pos;
            }
            const float cnt = (float)(128 - pos);
            const float pre = prow[130 + pos];
            const float num = cnt * a + 2.f * (total - pre);
            wacc += num / (cnt + EPS);
        }
    }

    #pragma unroll
    for (int o = 32; o > 0; o >>= 1) wacc += __shfl_xor(wacc, o, 64);
    if (lane == 0) red[w] = wacc;
    __syncthreads();
    if (threadIdx.x == 0) {
        float s = 0.f;
        #pragma unroll
        for (int i = 0; i < 8; i++) s += red[i];
        part[p] = s;
    }
}

// ---------------------------------------------------------------------------
// K3: final reduction of 256 partials -> scalar loss.
__global__ __launch_bounds__(256) void k_reduce(const float* __restrict__ part,
                                                float* __restrict__ out) {
    __shared__ float red[4];
    const int wid  = threadIdx.x >> 6;
    const int lane = threadIdx.x & 63;
    float s = part[threadIdx.x];
    #pragma unroll
    for (int o = 32; o > 0; o >>= 1) s += __shfl_xor(s, o, 64);
    if (lane == 0) red[wid] = s;
    __syncthreads();
    if (threadIdx.x == 0) out[0] = (red[0] + red[1] + red[2] + red[3]) * INV_CNT;
}

// ---------------------------------------------------------------------------
extern "C" void kernel_launch(void* const* d_in, const int* in_sizes, int n_in,
                              void* d_out, int out_size, void* d_ws, size_t ws_size,
                              hipStream_t stream) {
    const float* latent = (const float*)d_in[0];
    float* out = (float*)d_out;
    char* wsb = (char*)d_ws;
    short* nrm  = (short*)(wsb + NORM_OFF);
    float* part = (float*)(wsb + PART_OFF);

    hipLaunchKernelGGL(k_normalize, dim3(2048), dim3(256), 0, stream, latent, nrm);
    hipLaunchKernelGGL(k_fused,     dim3(256),  dim3(512), 0, stream, nrm, part);
    hipLaunchKernelGGL(k_reduce,    dim3(1),    dim3(256), 0, stream, part, out);
}